// Round 2
// baseline (529.091 us; speedup 1.0000x reference)
//
#include <hip/hip_runtime.h>
#include <hip/hip_bf16.h>
#include <cstdint>
#include <cstddef>

#define D_MODEL 1024
#define NHEADS 16
#define HD 64
#define NB 2
#define SL 2048
#define SEQ (NB*SL)      // 4096
#define NQKV (3*D_MODEL) // 3072

typedef __attribute__((ext_vector_type(8))) short short8;
typedef __attribute__((ext_vector_type(4))) float floatx4;
typedef unsigned short u16;

__device__ __forceinline__ u16 f2bf(float f) {
    union { float f; uint32_t u; } v; v.f = f;
    return (u16)((v.u + 0x7fffu + ((v.u >> 16) & 1u)) >> 16);
}

// ---------------- fp32 -> bf16 convert (vectorized x4) ----------------
__global__ __launch_bounds__(256) void cvt_kernel(const float* __restrict__ in,
                                                  u16* __restrict__ out, int n4) {
    int i = blockIdx.x * 256 + threadIdx.x;
    if (i >= n4) return;
    float4 f = ((const float4*)in)[i];
    ushort4 o;
    o.x = f2bf(f.x); o.y = f2bf(f.y); o.z = f2bf(f.z); o.w = f2bf(f.w);
    ((ushort4*)out)[i] = o;
}

// ---------------- shared 64x64-per-wave GEMM core: C = A * B^T ----------------
__device__ __forceinline__ void gemm64x64(const u16* __restrict__ A,
                                          const u16* __restrict__ Bw,
                                          int mbase, int nbase, floatx4 acc[4][4]) {
    const int lane = threadIdx.x & 63;
    const int l15 = lane & 15, quad = lane >> 4;
    #pragma unroll
    for (int i = 0; i < 4; i++)
        #pragma unroll
        for (int j = 0; j < 4; j++)
            acc[i][j] = (floatx4){0.f, 0.f, 0.f, 0.f};
    const u16* Ap = A + (size_t)(mbase + l15) * 1024 + quad * 8;
    const u16* Bp = Bw + (size_t)(nbase + l15) * 1024 + quad * 8;
    for (int k0 = 0; k0 < 1024; k0 += 32) {
        short8 af[4], bf[4];
        #pragma unroll
        for (int i = 0; i < 4; i++) af[i] = *(const short8*)(Ap + i * 16 * 1024 + k0);
        #pragma unroll
        for (int j = 0; j < 4; j++) bf[j] = *(const short8*)(Bp + j * 16 * 1024 + k0);
        #pragma unroll
        for (int i = 0; i < 4; i++)
            #pragma unroll
            for (int j = 0; j < 4; j++)
                acc[i][j] = __builtin_amdgcn_mfma_f32_16x16x32_bf16(af[i], bf[j], acc[i][j], 0, 0, 0);
    }
}

// ---------------- QKV GEMM: [4096,1024] x [3072,1024]^T + bias ----------------
__global__ __launch_bounds__(256) void qkv_gemm(const u16* __restrict__ xb,
                                                const u16* __restrict__ wb,
                                                const float* __restrict__ bias,
                                                u16* __restrict__ Qo, u16* __restrict__ Ko,
                                                u16* __restrict__ Vt) {
    const int wave = threadIdx.x >> 6;
    const int wr = wave >> 1, wc = wave & 1;
    const int mbase = blockIdx.y * 128 + wr * 64;
    const int nbase = blockIdx.x * 128 + wc * 64;
    floatx4 acc[4][4];
    gemm64x64(xb, wb, mbase, nbase, acc);
    const int lane = threadIdx.x & 63;
    const int l15 = lane & 15, quad = lane >> 4;
    #pragma unroll
    for (int j = 0; j < 4; j++) {
        int n = nbase + j * 16 + l15;
        float bv = bias[n];
        int which = n >> 10;
        int within = n & 1023;
        int h = within >> 6, d = within & 63;
        #pragma unroll
        for (int i = 0; i < 4; i++) {
            #pragma unroll
            for (int r = 0; r < 4; r++) {
                int m = mbase + i * 16 + quad * 4 + r;
                int b = m >> 11, l = m & 2047;
                int bh = b * NHEADS + h;
                float v = acc[i][j][r] + bv;
                if (which == 0)      Qo[((size_t)bh * SL + l) * HD + d] = f2bf(v * 0.125f); // SCALE folded
                else if (which == 1) Ko[((size_t)bh * SL + l) * HD + d] = f2bf(v);
                else                 Vt[((size_t)bh * HD + d) * SL + l] = f2bf(v);
            }
        }
    }
}

// ---------------- Flash attention v2: S^T layout, 128-key tiles ----------------
// One block = (bh, 64 q-rows), 4 waves x 16 q-rows each.
// S^T = K·Q^T via MFMA: C col (lane&15) = q-row, C row (quad*4+r + 16*j) = key.
// => each lane owns ALL scores of q-row (lane&15): softmax is register-local,
//    only 2 cross-quad shuffles per reduction. P written to LDS in PV A-layout.
#define PSTRIDE 136  // u16 elems per P row: 128 + 8 pad (272 B, 16B-aligned rows)
__global__ __launch_bounds__(256) void flash_kernel(const u16* __restrict__ Q,
                                                    const u16* __restrict__ K,
                                                    const u16* __restrict__ V,
                                                    u16* __restrict__ AO) {
    __shared__ __align__(16) u16 pbuf[4][16][PSTRIDE];
    const int wave = threadIdx.x >> 6;
    const int lane = threadIdx.x & 63;
    const int l15 = lane & 15, quad = lane >> 4;
    const int bh = blockIdx.y;
    const int b = bh >> 4, h = bh & 15;
    const int qbase = blockIdx.x * 64 + wave * 16;
    const u16* Qp = Q + (size_t)bh * SL * HD;
    const u16* Kp = K + (size_t)bh * SL * HD;
    const u16* Vp = V + (size_t)bh * HD * SL;

    // Q fragments (B-operand now): B[n=q-row=l15][k=quad*8+..]; Q pre-scaled by 0.125
    short8 qf0 = *(const short8*)(Qp + (size_t)(qbase + l15) * HD + quad * 8);
    short8 qf1 = *(const short8*)(Qp + (size_t)(qbase + l15) * HD + 32 + quad * 8);

    floatx4 accO[4];
    #pragma unroll
    for (int d = 0; d < 4; d++) accO[d] = (floatx4){0.f, 0.f, 0.f, 0.f};
    float m_i = -__builtin_inff();   // per-lane state for q-row l15 (replicated across quads)
    float l_i = 0.f;

    for (int kt = 0; kt < SL; kt += 128) {
        // ---- S^T = K·Q^T : 8 key-tiles of 16, 2 ksteps each ----
        floatx4 s[8];
        #pragma unroll
        for (int j = 0; j < 8; j++) {
            const u16* kr = Kp + (size_t)(kt + j * 16 + l15) * HD + quad * 8;
            short8 ka = *(const short8*)(kr);
            short8 kb = *(const short8*)(kr + 32);
            floatx4 z = (floatx4){0.f, 0.f, 0.f, 0.f};
            z = __builtin_amdgcn_mfma_f32_16x16x32_bf16(ka, qf0, z, 0, 0, 0);
            s[j] = __builtin_amdgcn_mfma_f32_16x16x32_bf16(kb, qf1, z, 0, 0, 0);
        }
        // ---- per-lane softmax over 32 scores (keys quad*4+r + 16j) ----
        float mx = s[0][0];
        #pragma unroll
        for (int j = 0; j < 8; j++)
            #pragma unroll
            for (int r = 0; r < 4; r++) mx = fmaxf(mx, s[j][r]);
        mx = fmaxf(mx, __shfl_xor(mx, 16, 64));
        mx = fmaxf(mx, __shfl_xor(mx, 32, 64));
        float mnew = fmaxf(m_i, mx);
        float alpha = __expf(m_i - mnew);
        m_i = mnew;
        float rs = 0.f;
        #pragma unroll
        for (int j = 0; j < 8; j++) {
            float p0 = __expf(s[j][0] - mnew);
            float p1 = __expf(s[j][1] - mnew);
            float p2 = __expf(s[j][2] - mnew);
            float p3 = __expf(s[j][3] - mnew);
            rs += (p0 + p1) + (p2 + p3);
            ushort4 pk;
            pk.x = f2bf(p0); pk.y = f2bf(p1); pk.z = f2bf(p2); pk.w = f2bf(p3);
            *(ushort4*)(&pbuf[wave][l15][j * 16 + quad * 4]) = pk;  // ds_write_b64
        }
        rs += __shfl_xor(rs, 16, 64);
        rs += __shfl_xor(rs, 32, 64);
        l_i = l_i * alpha + rs;
        // ---- rescale O: alpha lives at lane l15==row; broadcast per acc row ----
        #pragma unroll
        for (int r = 0; r < 4; r++) {
            float a_r = __shfl(alpha, quad * 4 + r, 16);
            #pragma unroll
            for (int d = 0; d < 4; d++) accO[d][r] *= a_r;
        }
        // ---- PV: O += P·V ; A = P from LDS (intra-wave, no barrier), B = Vt rows ----
        #pragma unroll
        for (int ks = 0; ks < 4; ks++) {
            short8 pf = *(const short8*)(&pbuf[wave][l15][ks * 32 + quad * 8]); // ds_read_b128
            #pragma unroll
            for (int d = 0; d < 4; d++) {
                short8 vf = *(const short8*)(Vp + (size_t)(d * 16 + l15) * SL + kt + ks * 32 + quad * 8);
                accO[d] = __builtin_amdgcn_mfma_f32_16x16x32_bf16(pf, vf, accO[d], 0, 0, 0);
            }
        }
    }
    float invl = 1.f / l_i;
    #pragma unroll
    for (int r = 0; r < 4; r++) {
        float inv_r = __shfl(invl, quad * 4 + r, 16);
        int row = b * SL + qbase + quad * 4 + r;
        #pragma unroll
        for (int d = 0; d < 4; d++) {
            int col = h * HD + d * 16 + l15;
            AO[(size_t)row * D_MODEL + col] = f2bf(accO[d][r] * inv_r);
        }
    }
}

// ---------------- Output projection: [4096,1024] x [1024,1024]^T + bias -> fp32 ----------------
__global__ __launch_bounds__(256) void proj_gemm(const u16* __restrict__ ab,
                                                 const u16* __restrict__ wb,
                                                 const float* __restrict__ bias,
                                                 float* __restrict__ out) {
    const int wave = threadIdx.x >> 6;
    const int wr = wave >> 1, wc = wave & 1;
    const int mbase = blockIdx.y * 128 + wr * 64;
    const int nbase = blockIdx.x * 128 + wc * 64;
    floatx4 acc[4][4];
    gemm64x64(ab, wb, mbase, nbase, acc);
    const int lane = threadIdx.x & 63;
    const int l15 = lane & 15, quad = lane >> 4;
    #pragma unroll
    for (int j = 0; j < 4; j++) {
        int n = nbase + j * 16 + l15;
        float bv = bias[n];
        #pragma unroll
        for (int i = 0; i < 4; i++) {
            #pragma unroll
            for (int r = 0; r < 4; r++) {
                int m = mbase + i * 16 + quad * 4 + r;
                out[(size_t)m * D_MODEL + n] = acc[i][j][r] + bv;
            }
        }
    }
}

extern "C" void kernel_launch(void* const* d_in, const int* in_sizes, int n_in,
                              void* d_out, int out_size, void* d_ws, size_t ws_size,
                              hipStream_t stream) {
    const float* x      = (const float*)d_in[0];
    const float* qkv_w  = (const float*)d_in[1];
    const float* qkv_b  = (const float*)d_in[2];
    const float* proj_w = (const float*)d_in[3];
    const float* proj_b = (const float*)d_in[4];
    float* out = (float*)d_out;
    char* ws = (char*)d_ws;

    u16* xb    = (u16*)(ws);             // x bf16        [4096,1024]   8 MB
    u16* wqkv  = (u16*)(ws + 8388608);   // qkv_w bf16    [3072,1024]   6 MB
    u16* wproj = (u16*)(ws + 14680064);  // proj_w bf16   [1024,1024]   2 MB
    u16* Qb    = (u16*)(ws + 16777216);  // Q bf16        [32][2048][64] 8 MB (pre-scaled)
    u16* Kb    = (u16*)(ws + 25165824);  // K bf16        [32][2048][64] 8 MB
    u16* Vt    = (u16*)(ws + 33554432);  // V^T bf16      [32][64][2048] 8 MB
    u16* AO    = (u16*)(ws + 41943040);  // attn out bf16 [4096,1024]    8 MB

    cvt_kernel<<<4096, 256, 0, stream>>>(x, xb, 4194304 / 4);
    cvt_kernel<<<3072, 256, 0, stream>>>(qkv_w, wqkv, 3145728 / 4);
    cvt_kernel<<<1024, 256, 0, stream>>>(proj_w, wproj, 1048576 / 4);
    qkv_gemm<<<dim3(NQKV / 128, SEQ / 128), 256, 0, stream>>>(xb, wqkv, qkv_b, Qb, Kb, Vt);
    flash_kernel<<<dim3(SL / 64, NB * NHEADS), 256, 0, stream>>>(Qb, Kb, Vt, AO);
    proj_gemm<<<dim3(D_MODEL / 128, SEQ / 128), 256, 0, stream>>>(AO, wproj, proj_b, out);
}

// Round 3
// 296.882 us; speedup vs baseline: 1.7822x; 1.7822x over previous
//
#include <hip/hip_runtime.h>
#include <hip/hip_bf16.h>
#include <cstdint>
#include <cstddef>

#define D_MODEL 1024
#define NHEADS 16
#define HD 64
#define NB 2
#define SL 2048
#define SEQ (NB*SL)      // 4096
#define NQKV (3*D_MODEL) // 3072

typedef __attribute__((ext_vector_type(8))) short short8;
typedef __attribute__((ext_vector_type(4))) float floatx4;
typedef unsigned short u16;

__device__ __forceinline__ u16 f2bf(float f) {
    union { float f; uint32_t u; } v; v.f = f;
    return (u16)((v.u + 0x7fffu + ((v.u >> 16) & 1u)) >> 16);
}

// ---------------- fp32 -> bf16 convert (vectorized x4) ----------------
__global__ __launch_bounds__(256) void cvt_kernel(const float* __restrict__ in,
                                                  u16* __restrict__ out, int n4) {
    int i = blockIdx.x * 256 + threadIdx.x;
    if (i >= n4) return;
    float4 f = ((const float4*)in)[i];
    ushort4 o;
    o.x = f2bf(f.x); o.y = f2bf(f.y); o.z = f2bf(f.z); o.w = f2bf(f.w);
    ((ushort4*)out)[i] = o;
}

// ---------------- shared 64x64-per-wave GEMM core: C = A * B^T ----------------
__device__ __forceinline__ void gemm64x64(const u16* __restrict__ A,
                                          const u16* __restrict__ Bw,
                                          int mbase, int nbase, floatx4 acc[4][4]) {
    const int lane = threadIdx.x & 63;
    const int l15 = lane & 15, quad = lane >> 4;
    #pragma unroll
    for (int i = 0; i < 4; i++)
        #pragma unroll
        for (int j = 0; j < 4; j++)
            acc[i][j] = (floatx4){0.f, 0.f, 0.f, 0.f};
    const u16* Ap = A + (size_t)(mbase + l15) * 1024 + quad * 8;
    const u16* Bp = Bw + (size_t)(nbase + l15) * 1024 + quad * 8;
    for (int k0 = 0; k0 < 1024; k0 += 32) {
        short8 af[4], bf[4];
        #pragma unroll
        for (int i = 0; i < 4; i++) af[i] = *(const short8*)(Ap + i * 16 * 1024 + k0);
        #pragma unroll
        for (int j = 0; j < 4; j++) bf[j] = *(const short8*)(Bp + j * 16 * 1024 + k0);
        #pragma unroll
        for (int i = 0; i < 4; i++)
            #pragma unroll
            for (int j = 0; j < 4; j++)
                acc[i][j] = __builtin_amdgcn_mfma_f32_16x16x32_bf16(af[i], bf[j], acc[i][j], 0, 0, 0);
    }
}

// ---------------- QKV GEMM: [4096,1024] x [3072,1024]^T + bias ----------------
__global__ __launch_bounds__(256) void qkv_gemm(const u16* __restrict__ xb,
                                                const u16* __restrict__ wb,
                                                const float* __restrict__ bias,
                                                u16* __restrict__ Qo, u16* __restrict__ Ko,
                                                u16* __restrict__ Vt) {
    const int wave = threadIdx.x >> 6;
    const int wr = wave >> 1, wc = wave & 1;
    const int mbase = blockIdx.y * 128 + wr * 64;
    const int nbase = blockIdx.x * 128 + wc * 64;
    floatx4 acc[4][4];
    gemm64x64(xb, wb, mbase, nbase, acc);
    const int lane = threadIdx.x & 63;
    const int l15 = lane & 15, quad = lane >> 4;
    #pragma unroll
    for (int j = 0; j < 4; j++) {
        int n = nbase + j * 16 + l15;
        float bv = bias[n];
        int which = n >> 10;
        int within = n & 1023;
        int h = within >> 6, d = within & 63;
        #pragma unroll
        for (int i = 0; i < 4; i++) {
            #pragma unroll
            for (int r = 0; r < 4; r++) {
                int m = mbase + i * 16 + quad * 4 + r;
                int b = m >> 11, l = m & 2047;
                int bh = b * NHEADS + h;
                float v = acc[i][j][r] + bv;
                if (which == 0)      Qo[((size_t)bh * SL + l) * HD + d] = f2bf(v * 0.125f); // SCALE folded
                else if (which == 1) Ko[((size_t)bh * SL + l) * HD + d] = f2bf(v);
                else                 Vt[((size_t)bh * HD + d) * SL + l] = f2bf(v);
            }
        }
    }
}

// ---------------- Flash attention v3: S^T layout + cooperative LDS staging ----------------
// Block = (bh, 64 q-rows), 4 waves x 16 q-rows. Per 128-key tile:
//   stage K[128x64] (LDS stride 72 u16) + V[64x128] (stride 136 u16) cooperatively,
//   2-barrier m97 structure; compute phase touches LDS only.
// K frag read bank = 4*(l15+quad) mod 32 -> b128 conflict-free floor (8 cyc).
#define KSTR 72    // u16 stride for K rows (64 data + 8 pad = 144 B)
#define VSTR 136   // u16 stride for V rows (128 data + 8 pad = 272 B)
#define PSTRIDE 136
__global__ __launch_bounds__(256) void flash_kernel(const u16* __restrict__ Q,
                                                    const u16* __restrict__ K,
                                                    const u16* __restrict__ V,
                                                    u16* __restrict__ AO) {
    __shared__ __align__(16) u16 Klds[128 * KSTR];        // 18432 B
    __shared__ __align__(16) u16 Vlds[64 * VSTR];         // 17408 B
    __shared__ __align__(16) u16 pbuf[4][16][PSTRIDE];    // 17408 B
    const int tid = threadIdx.x;
    const int wave = tid >> 6;
    const int lane = tid & 63;
    const int l15 = lane & 15, quad = lane >> 4;
    const int bh = blockIdx.y;
    const int b = bh >> 4, h = bh & 15;
    const int qbase = blockIdx.x * 64 + wave * 16;
    const u16* Qp = Q + (size_t)bh * SL * HD;
    const u16* Kp = K + (size_t)bh * SL * HD;
    const u16* Vp = V + (size_t)bh * HD * SL;

    // Q fragments (B-operand): B[n=q-row=l15][k=quad*8+..]; Q pre-scaled by 0.125
    short8 qf0 = *(const short8*)(Qp + (size_t)(qbase + l15) * HD + quad * 8);
    short8 qf1 = *(const short8*)(Qp + (size_t)(qbase + l15) * HD + 32 + quad * 8);

    floatx4 accO[4];
    #pragma unroll
    for (int d = 0; d < 4; d++) accO[d] = (floatx4){0.f, 0.f, 0.f, 0.f};
    float m_i = -__builtin_inff();   // per-lane state for q-row l15 (replicated across quads)
    float l_i = 0.f;

    for (int kt = 0; kt < SL; kt += 128) {
        // ---- stage: batched global loads (all in flight together) ----
        short8 kreg[4], vreg[4];
        #pragma unroll
        for (int it = 0; it < 4; it++) {
            int c = it * 256 + tid;               // K chunk: row=c>>3 (0..127), grp=c&7
            kreg[it] = *(const short8*)(Kp + (size_t)(kt + (c >> 3)) * HD + (c & 7) * 8);
        }
        #pragma unroll
        for (int it = 0; it < 4; it++) {
            int c = it * 256 + tid;               // V chunk: row=c>>4 (0..63), grp=c&15
            vreg[it] = *(const short8*)(Vp + (size_t)(c >> 4) * SL + kt + (c & 15) * 8);
        }
        __syncthreads();   // WAR: all waves done reading previous tile's LDS
        #pragma unroll
        for (int it = 0; it < 4; it++) {
            int c = it * 256 + tid;
            *(short8*)(&Klds[(c >> 3) * KSTR + (c & 7) * 8]) = kreg[it];
        }
        #pragma unroll
        for (int it = 0; it < 4; it++) {
            int c = it * 256 + tid;
            *(short8*)(&Vlds[(c >> 4) * VSTR + (c & 15) * 8]) = vreg[it];
        }
        __syncthreads();   // staging visible to all waves

        // ---- S^T = K·Q^T from LDS: 8 key-subtiles of 16 ----
        floatx4 s[8];
        #pragma unroll
        for (int j = 0; j < 8; j++) {
            const u16* kr = &Klds[(j * 16 + l15) * KSTR + quad * 8];
            short8 ka = *(const short8*)(kr);
            short8 kb = *(const short8*)(kr + 32);
            floatx4 z = (floatx4){0.f, 0.f, 0.f, 0.f};
            z = __builtin_amdgcn_mfma_f32_16x16x32_bf16(ka, qf0, z, 0, 0, 0);
            s[j] = __builtin_amdgcn_mfma_f32_16x16x32_bf16(kb, qf1, s[j] = z, 0, 0, 0);
        }
        // ---- per-lane online softmax over 32 scores ----
        float mx = s[0][0];
        #pragma unroll
        for (int j = 0; j < 8; j++)
            #pragma unroll
            for (int r = 0; r < 4; r++) mx = fmaxf(mx, s[j][r]);
        mx = fmaxf(mx, __shfl_xor(mx, 16, 64));
        mx = fmaxf(mx, __shfl_xor(mx, 32, 64));
        float mnew = fmaxf(m_i, mx);
        float alpha = __expf(m_i - mnew);
        m_i = mnew;
        float rs = 0.f;
        #pragma unroll
        for (int j = 0; j < 8; j++) {
            float p0 = __expf(s[j][0] - mnew);
            float p1 = __expf(s[j][1] - mnew);
            float p2 = __expf(s[j][2] - mnew);
            float p3 = __expf(s[j][3] - mnew);
            rs += (p0 + p1) + (p2 + p3);
            ushort4 pk;
            pk.x = f2bf(p0); pk.y = f2bf(p1); pk.z = f2bf(p2); pk.w = f2bf(p3);
            *(ushort4*)(&pbuf[wave][l15][j * 16 + quad * 4]) = pk;  // ds_write_b64
        }
        rs += __shfl_xor(rs, 16, 64);
        rs += __shfl_xor(rs, 32, 64);
        l_i = l_i * alpha + rs;
        // ---- rescale O ----
        #pragma unroll
        for (int r = 0; r < 4; r++) {
            float a_r = __shfl(alpha, quad * 4 + r, 16);
            #pragma unroll
            for (int d = 0; d < 4; d++) accO[d][r] *= a_r;
        }
        // ---- PV from LDS (P intra-wave, V block-shared) ----
        #pragma unroll
        for (int ks = 0; ks < 4; ks++) {
            short8 pf = *(const short8*)(&pbuf[wave][l15][ks * 32 + quad * 8]); // ds_read_b128
            #pragma unroll
            for (int d = 0; d < 4; d++) {
                short8 vf = *(const short8*)(&Vlds[(d * 16 + l15) * VSTR + ks * 32 + quad * 8]);
                accO[d] = __builtin_amdgcn_mfma_f32_16x16x32_bf16(pf, vf, accO[d], 0, 0, 0);
            }
        }
    }
    float invl = 1.f / l_i;
    #pragma unroll
    for (int r = 0; r < 4; r++) {
        float inv_r = __shfl(invl, quad * 4 + r, 16);
        int row = b * SL + qbase + quad * 4 + r;
        #pragma unroll
        for (int d = 0; d < 4; d++) {
            int col = h * HD + d * 16 + l15;
            AO[(size_t)row * D_MODEL + col] = f2bf(accO[d][r] * inv_r);
        }
    }
}

// ---------------- Output projection: [4096,1024] x [1024,1024]^T + bias -> fp32 ----------------
__global__ __launch_bounds__(256) void proj_gemm(const u16* __restrict__ ab,
                                                 const u16* __restrict__ wb,
                                                 const float* __restrict__ bias,
                                                 float* __restrict__ out) {
    const int wave = threadIdx.x >> 6;
    const int wr = wave >> 1, wc = wave & 1;
    const int mbase = blockIdx.y * 128 + wr * 64;
    const int nbase = blockIdx.x * 128 + wc * 64;
    floatx4 acc[4][4];
    gemm64x64(ab, wb, mbase, nbase, acc);
    const int lane = threadIdx.x & 63;
    const int l15 = lane & 15, quad = lane >> 4;
    #pragma unroll
    for (int j = 0; j < 4; j++) {
        int n = nbase + j * 16 + l15;
        float bv = bias[n];
        #pragma unroll
        for (int i = 0; i < 4; i++) {
            #pragma unroll
            for (int r = 0; r < 4; r++) {
                int m = mbase + i * 16 + quad * 4 + r;
                out[(size_t)m * D_MODEL + n] = acc[i][j][r] + bv;
            }
        }
    }
}

extern "C" void kernel_launch(void* const* d_in, const int* in_sizes, int n_in,
                              void* d_out, int out_size, void* d_ws, size_t ws_size,
                              hipStream_t stream) {
    const float* x      = (const float*)d_in[0];
    const float* qkv_w  = (const float*)d_in[1];
    const float* qkv_b  = (const float*)d_in[2];
    const float* proj_w = (const float*)d_in[3];
    const float* proj_b = (const float*)d_in[4];
    float* out = (float*)d_out;
    char* ws = (char*)d_ws;

    u16* xb    = (u16*)(ws);             // x bf16        [4096,1024]   8 MB
    u16* wqkv  = (u16*)(ws + 8388608);   // qkv_w bf16    [3072,1024]   6 MB
    u16* wproj = (u16*)(ws + 14680064);  // proj_w bf16   [1024,1024]   2 MB
    u16* Qb    = (u16*)(ws + 16777216);  // Q bf16        [32][2048][64] 8 MB (pre-scaled)
    u16* Kb    = (u16*)(ws + 25165824);  // K bf16        [32][2048][64] 8 MB
    u16* Vt    = (u16*)(ws + 33554432);  // V^T bf16      [32][64][2048] 8 MB
    u16* AO    = (u16*)(ws + 41943040);  // attn out bf16 [4096,1024]    8 MB

    cvt_kernel<<<4096, 256, 0, stream>>>(x, xb, 4194304 / 4);
    cvt_kernel<<<3072, 256, 0, stream>>>(qkv_w, wqkv, 3145728 / 4);
    cvt_kernel<<<1024, 256, 0, stream>>>(proj_w, wproj, 1048576 / 4);
    qkv_gemm<<<dim3(NQKV / 128, SEQ / 128), 256, 0, stream>>>(xb, wqkv, qkv_b, Qb, Kb, Vt);
    flash_kernel<<<dim3(SL / 64, NB * NHEADS), 256, 0, stream>>>(Qb, Kb, Vt, AO);
    proj_gemm<<<dim3(D_MODEL / 128, SEQ / 128), 256, 0, stream>>>(AO, wproj, proj_b, out);
}

// Round 4
// 229.405 us; speedup vs baseline: 2.3064x; 1.2941x over previous
//
#include <hip/hip_runtime.h>
#include <hip/hip_bf16.h>
#include <cstdint>
#include <cstddef>

#define D_MODEL 1024
#define NHEADS 16
#define HD 64
#define NB 2
#define SL 2048
#define SEQ (NB*SL)      // 4096
#define NQKV (3*D_MODEL) // 3072

typedef __attribute__((ext_vector_type(8))) short short8;
typedef __attribute__((ext_vector_type(4))) float floatx4;
typedef unsigned short u16;

__device__ __forceinline__ u16 f2bf(float f) {
    union { float f; uint32_t u; } v; v.f = f;
    return (u16)((v.u + 0x7fffu + ((v.u >> 16) & 1u)) >> 16);
}

// ---------------- fp32 -> bf16 convert (vectorized x4) ----------------
__global__ __launch_bounds__(256) void cvt_kernel(const float* __restrict__ in,
                                                  u16* __restrict__ out, int n4) {
    int i = blockIdx.x * 256 + threadIdx.x;
    if (i >= n4) return;
    float4 f = ((const float4*)in)[i];
    ushort4 o;
    o.x = f2bf(f.x); o.y = f2bf(f.y); o.z = f2bf(f.z); o.w = f2bf(f.w);
    ((ushort4*)out)[i] = o;
}

// ---------------- m97-style staged 128x128 GEMM mainloop: C = A * B^T ----------------
// A [M,K] bf16 row-major, B [N,K] bf16 row-major. Block = 128M x 128N, 4 waves
// in 2x2; each wave 64x64 = 4x4 MFMA tiles. BK=32. LDS tiles are UNPADDED
// row-major [128][32] u16 (global_load_lds dest = wave-uniform base + lane*16B,
// so the layout is contiguous-by-construction).
__device__ __forceinline__ void gemm128_staged(const u16* __restrict__ A,
                                               const u16* __restrict__ B,
                                               int mbase, int nbase, int K,
                                               u16* Alds, u16* Blds,
                                               floatx4 acc[4][4]) {
    const int tid = threadIdx.x;
    const int lane = tid & 63;
    const int l15 = lane & 15, quad = lane >> 4;
    const int wave = tid >> 6;
    const int wr = wave >> 1, wc = wave & 1;
    #pragma unroll
    for (int i = 0; i < 4; i++)
        #pragma unroll
        for (int j = 0; j < 4; j++)
            acc[i][j] = (floatx4){0.f, 0.f, 0.f, 0.f};

    // staging chunk c = issue*256 + tid : row = c>>2 (0..127), kgrp = (c&3)*8
    const int r0 = tid >> 2, kg0 = (tid & 3) * 8;           // issue 0
    const int r1 = (256 + tid) >> 2, kg1 = kg0;             // issue 1 (row +64)
    const u16* Arow0 = A + (size_t)(mbase + r0) * K + kg0;
    const u16* Arow1 = A + (size_t)(mbase + r1) * K + kg1;
    const u16* Brow0 = B + (size_t)(nbase + r0) * K + kg0;
    const u16* Brow1 = B + (size_t)(nbase + r1) * K + kg1;

    for (int k0 = 0; k0 < K; k0 += 32) {
        __syncthreads();   // WAR: all waves done reading previous tile
        __builtin_amdgcn_global_load_lds(
            (const __attribute__((address_space(1))) void*)(Arow0 + k0),
            (__attribute__((address_space(3))) void*)(Alds + tid * 8), 16, 0, 0);
        __builtin_amdgcn_global_load_lds(
            (const __attribute__((address_space(1))) void*)(Arow1 + k0),
            (__attribute__((address_space(3))) void*)(Alds + (256 + tid) * 8), 16, 0, 0);
        __builtin_amdgcn_global_load_lds(
            (const __attribute__((address_space(1))) void*)(Brow0 + k0),
            (__attribute__((address_space(3))) void*)(Blds + tid * 8), 16, 0, 0);
        __builtin_amdgcn_global_load_lds(
            (const __attribute__((address_space(1))) void*)(Brow1 + k0),
            (__attribute__((address_space(3))) void*)(Blds + (256 + tid) * 8), 16, 0, 0);
        __syncthreads();   // drains vmcnt: staged tile visible

        short8 af[4], bf[4];
        #pragma unroll
        for (int i = 0; i < 4; i++)
            af[i] = *(const short8*)(Alds + (wr * 64 + i * 16 + l15) * 32 + quad * 8);
        #pragma unroll
        for (int j = 0; j < 4; j++)
            bf[j] = *(const short8*)(Blds + (wc * 64 + j * 16 + l15) * 32 + quad * 8);
        #pragma unroll
        for (int i = 0; i < 4; i++)
            #pragma unroll
            for (int j = 0; j < 4; j++)
                acc[i][j] = __builtin_amdgcn_mfma_f32_16x16x32_bf16(af[i], bf[j], acc[i][j], 0, 0, 0);
    }
}

// ---------------- QKV GEMM: [4096,1024] x [3072,1024]^T + bias ----------------
__global__ __launch_bounds__(256) void qkv_gemm(const u16* __restrict__ xb,
                                                const u16* __restrict__ wb,
                                                const float* __restrict__ bias,
                                                u16* __restrict__ Qo, u16* __restrict__ Ko,
                                                u16* __restrict__ Vt) {
    __shared__ __align__(16) u16 Alds[128 * 32];
    __shared__ __align__(16) u16 Blds[128 * 32];
    const int mbase = blockIdx.y * 128;
    const int nbase = blockIdx.x * 128;
    floatx4 acc[4][4];
    gemm128_staged(xb, wb, mbase, nbase, 1024, Alds, Blds, acc);
    const int lane = threadIdx.x & 63;
    const int wave = threadIdx.x >> 6;
    const int wr = wave >> 1, wc = wave & 1;
    const int l15 = lane & 15, quad = lane >> 4;
    #pragma unroll
    for (int j = 0; j < 4; j++) {
        int n = nbase + wc * 64 + j * 16 + l15;
        float bv = bias[n];
        int which = n >> 10;
        int within = n & 1023;
        int h = within >> 6, d = within & 63;
        #pragma unroll
        for (int i = 0; i < 4; i++) {
            #pragma unroll
            for (int r = 0; r < 4; r++) {
                int m = mbase + wr * 64 + i * 16 + quad * 4 + r;
                int b = m >> 11, l = m & 2047;
                int bh = b * NHEADS + h;
                float v = acc[i][j][r] + bv;
                if (which == 0)      Qo[((size_t)bh * SL + l) * HD + d] = f2bf(v * 0.125f); // SCALE folded
                else if (which == 1) Ko[((size_t)bh * SL + l) * HD + d] = f2bf(v);
                else                 Vt[((size_t)bh * HD + d) * SL + l] = f2bf(v);
            }
        }
    }
}

// ---------------- Flash attention v3: S^T layout + cooperative LDS staging ----------------
#define KSTR 72    // u16 stride for K rows (64 data + 8 pad = 144 B)
#define VSTR 136   // u16 stride for V rows (128 data + 8 pad = 272 B)
#define PSTRIDE 136
__global__ __launch_bounds__(256) void flash_kernel(const u16* __restrict__ Q,
                                                    const u16* __restrict__ K,
                                                    const u16* __restrict__ V,
                                                    u16* __restrict__ AO) {
    __shared__ __align__(16) u16 Klds[128 * KSTR];        // 18432 B
    __shared__ __align__(16) u16 Vlds[64 * VSTR];         // 17408 B
    __shared__ __align__(16) u16 pbuf[4][16][PSTRIDE];    // 17408 B
    const int tid = threadIdx.x;
    const int wave = tid >> 6;
    const int lane = tid & 63;
    const int l15 = lane & 15, quad = lane >> 4;
    const int bh = blockIdx.y;
    const int b = bh >> 4, h = bh & 15;
    const int qbase = blockIdx.x * 64 + wave * 16;
    const u16* Qp = Q + (size_t)bh * SL * HD;
    const u16* Kp = K + (size_t)bh * SL * HD;
    const u16* Vp = V + (size_t)bh * HD * SL;

    short8 qf0 = *(const short8*)(Qp + (size_t)(qbase + l15) * HD + quad * 8);
    short8 qf1 = *(const short8*)(Qp + (size_t)(qbase + l15) * HD + 32 + quad * 8);

    floatx4 accO[4];
    #pragma unroll
    for (int d = 0; d < 4; d++) accO[d] = (floatx4){0.f, 0.f, 0.f, 0.f};
    float m_i = -__builtin_inff();
    float l_i = 0.f;

    for (int kt = 0; kt < SL; kt += 128) {
        short8 kreg[4], vreg[4];
        #pragma unroll
        for (int it = 0; it < 4; it++) {
            int c = it * 256 + tid;
            kreg[it] = *(const short8*)(Kp + (size_t)(kt + (c >> 3)) * HD + (c & 7) * 8);
        }
        #pragma unroll
        for (int it = 0; it < 4; it++) {
            int c = it * 256 + tid;
            vreg[it] = *(const short8*)(Vp + (size_t)(c >> 4) * SL + kt + (c & 15) * 8);
        }
        __syncthreads();
        #pragma unroll
        for (int it = 0; it < 4; it++) {
            int c = it * 256 + tid;
            *(short8*)(&Klds[(c >> 3) * KSTR + (c & 7) * 8]) = kreg[it];
        }
        #pragma unroll
        for (int it = 0; it < 4; it++) {
            int c = it * 256 + tid;
            *(short8*)(&Vlds[(c >> 4) * VSTR + (c & 15) * 8]) = vreg[it];
        }
        __syncthreads();

        floatx4 s[8];
        #pragma unroll
        for (int j = 0; j < 8; j++) {
            const u16* kr = &Klds[(j * 16 + l15) * KSTR + quad * 8];
            short8 ka = *(const short8*)(kr);
            short8 kb = *(const short8*)(kr + 32);
            floatx4 z = (floatx4){0.f, 0.f, 0.f, 0.f};
            z = __builtin_amdgcn_mfma_f32_16x16x32_bf16(ka, qf0, z, 0, 0, 0);
            s[j] = __builtin_amdgcn_mfma_f32_16x16x32_bf16(kb, qf1, z, 0, 0, 0);
        }
        float mx = s[0][0];
        #pragma unroll
        for (int j = 0; j < 8; j++)
            #pragma unroll
            for (int r = 0; r < 4; r++) mx = fmaxf(mx, s[j][r]);
        mx = fmaxf(mx, __shfl_xor(mx, 16, 64));
        mx = fmaxf(mx, __shfl_xor(mx, 32, 64));
        float mnew = fmaxf(m_i, mx);
        float alpha = __expf(m_i - mnew);
        m_i = mnew;
        float rs = 0.f;
        #pragma unroll
        for (int j = 0; j < 8; j++) {
            float p0 = __expf(s[j][0] - mnew);
            float p1 = __expf(s[j][1] - mnew);
            float p2 = __expf(s[j][2] - mnew);
            float p3 = __expf(s[j][3] - mnew);
            rs += (p0 + p1) + (p2 + p3);
            ushort4 pk;
            pk.x = f2bf(p0); pk.y = f2bf(p1); pk.z = f2bf(p2); pk.w = f2bf(p3);
            *(ushort4*)(&pbuf[wave][l15][j * 16 + quad * 4]) = pk;
        }
        rs += __shfl_xor(rs, 16, 64);
        rs += __shfl_xor(rs, 32, 64);
        l_i = l_i * alpha + rs;
        #pragma unroll
        for (int r = 0; r < 4; r++) {
            float a_r = __shfl(alpha, quad * 4 + r, 16);
            #pragma unroll
            for (int d = 0; d < 4; d++) accO[d][r] *= a_r;
        }
        #pragma unroll
        for (int ks = 0; ks < 4; ks++) {
            short8 pf = *(const short8*)(&pbuf[wave][l15][ks * 32 + quad * 8]);
            #pragma unroll
            for (int d = 0; d < 4; d++) {
                short8 vf = *(const short8*)(&Vlds[(d * 16 + l15) * VSTR + ks * 32 + quad * 8]);
                accO[d] = __builtin_amdgcn_mfma_f32_16x16x32_bf16(pf, vf, accO[d], 0, 0, 0);
            }
        }
    }
    float invl = 1.f / l_i;
    #pragma unroll
    for (int r = 0; r < 4; r++) {
        float inv_r = __shfl(invl, quad * 4 + r, 16);
        int row = b * SL + qbase + quad * 4 + r;
        #pragma unroll
        for (int d = 0; d < 4; d++) {
            int col = h * HD + d * 16 + l15;
            AO[(size_t)row * D_MODEL + col] = f2bf(accO[d][r] * inv_r);
        }
    }
}

// ---------------- Output projection: [4096,1024] x [1024,1024]^T + bias -> fp32 ----------------
__global__ __launch_bounds__(256) void proj_gemm(const u16* __restrict__ ab,
                                                 const u16* __restrict__ wb,
                                                 const float* __restrict__ bias,
                                                 float* __restrict__ out) {
    __shared__ __align__(16) u16 Alds[128 * 32];
    __shared__ __align__(16) u16 Blds[128 * 32];
    const int mbase = blockIdx.y * 128;
    const int nbase = blockIdx.x * 128;
    floatx4 acc[4][4];
    gemm128_staged(ab, wb, mbase, nbase, 1024, Alds, Blds, acc);
    const int lane = threadIdx.x & 63;
    const int wave = threadIdx.x >> 6;
    const int wr = wave >> 1, wc = wave & 1;
    const int l15 = lane & 15, quad = lane >> 4;
    #pragma unroll
    for (int j = 0; j < 4; j++) {
        int n = nbase + wc * 64 + j * 16 + l15;
        float bv = bias[n];
        #pragma unroll
        for (int i = 0; i < 4; i++) {
            #pragma unroll
            for (int r = 0; r < 4; r++) {
                int m = mbase + wr * 64 + i * 16 + quad * 4 + r;
                out[(size_t)m * D_MODEL + n] = acc[i][j][r] + bv;
            }
        }
    }
}

extern "C" void kernel_launch(void* const* d_in, const int* in_sizes, int n_in,
                              void* d_out, int out_size, void* d_ws, size_t ws_size,
                              hipStream_t stream) {
    const float* x      = (const float*)d_in[0];
    const float* qkv_w  = (const float*)d_in[1];
    const float* qkv_b  = (const float*)d_in[2];
    const float* proj_w = (const float*)d_in[3];
    const float* proj_b = (const float*)d_in[4];
    float* out = (float*)d_out;
    char* ws = (char*)d_ws;

    u16* xb    = (u16*)(ws);             // x bf16        [4096,1024]   8 MB
    u16* wqkv  = (u16*)(ws + 8388608);   // qkv_w bf16    [3072,1024]   6 MB
    u16* wproj = (u16*)(ws + 14680064);  // proj_w bf16   [1024,1024]   2 MB
    u16* Qb    = (u16*)(ws + 16777216);  // Q bf16        [32][2048][64] 8 MB (pre-scaled)
    u16* Kb    = (u16*)(ws + 25165824);  // K bf16        [32][2048][64] 8 MB
    u16* Vt    = (u16*)(ws + 33554432);  // V^T bf16      [32][64][2048] 8 MB
    u16* AO    = (u16*)(ws + 41943040);  // attn out bf16 [4096,1024]    8 MB

    cvt_kernel<<<4096, 256, 0, stream>>>(x, xb, 4194304 / 4);
    cvt_kernel<<<3072, 256, 0, stream>>>(qkv_w, wqkv, 3145728 / 4);
    cvt_kernel<<<1024, 256, 0, stream>>>(proj_w, wproj, 1048576 / 4);
    qkv_gemm<<<dim3(NQKV / 128, SEQ / 128), 256, 0, stream>>>(xb, wqkv, qkv_b, Qb, Kb, Vt);
    flash_kernel<<<dim3(SL / 64, NB * NHEADS), 256, 0, stream>>>(Qb, Kb, Vt, AO);
    proj_gemm<<<dim3(D_MODEL / 128, SEQ / 128), 256, 0, stream>>>(AO, wproj, proj_b, out);
}